// Round 7
// baseline (230.895 us; speedup 1.0000x reference)
//
#include <hip/hip_runtime.h>
#include <hip/hip_bf16.h>

#define B_    2
#define N_    6400
#define CD_   128
#define CM_   64
#define SEG_  20
#define JSEG_ (N_ / SEG_)    // 320
#define JT_   64
#define NJT_  (JSEG_ / JT_)  // 5
#define NBIT_ 100            // i-tiles of 128 total (2 b x 50)
#define LOG2E_ 1.44269504f
#define C2_    36.0673757f   // 25 * log2(e)

typedef __attribute__((ext_vector_type(8)))  short bf16x8;
typedef __attribute__((ext_vector_type(16))) float f32x16;

static __device__ __forceinline__ unsigned pack2bf(float a, float b) {
    union { float f; unsigned u; } x, y; x.f = a; y.f = b;
    return __builtin_amdgcn_perm(y.u + 0x8000u, x.u + 0x8000u, 0x07060302u);
}
static __device__ __forceinline__ float blo(unsigned u) {
    union { unsigned u; float f; } c; c.u = u << 16; return c.f;
}
static __device__ __forceinline__ float bhi(unsigned u) {
    union { unsigned u; float f; } c; c.u = u & 0xffff0000u; return c.f;
}
// pack 4 floats -> 4 fp8 e4m3 bytes
static __device__ __forceinline__ unsigned pack4fp8(float a, float b, float c, float d) {
    int w = __builtin_amdgcn_cvt_pk_fp8_f32(a, b, 0, false);
    w = __builtin_amdgcn_cvt_pk_fp8_f32(c, d, w, true);
    return (unsigned)w;
}

// ---------------- fused projections ----------------
// blocks [0,400): q (fp8, pre-scaled by log2e) from z_hsi; [400,800): k (fp8), v (bf16)
// qb8[b][i][o], kb8[b][j][o] (fp8 e4m3, 128B rows), vb[b][o][j] (bf16)
__global__ __launch_bounds__(256, 4)
void proj4(const float* __restrict__ zh, const float* __restrict__ zm,
           const float* __restrict__ Wq, const float* __restrict__ bq,
           const float* __restrict__ Wk, const float* __restrict__ bk,
           const float* __restrict__ Wv, const float* __restrict__ bv,
           unsigned char* __restrict__ qb8, unsigned char* __restrict__ kb8,
           short* __restrict__ vb)
{
    __shared__ float zt[128 * 36];   // [c][i 32], stride 36
    const int tid = threadIdx.x;
    int bid = blockIdx.x;
    const int qmode = bid < 400;
    if (!qmode) bid -= 400;
    const int b  = bid / 200;
    const int r  = bid % 200;
    const int i0 = r * 32;
    const int ig = tid & 7, og = tid >> 3;       // 8 i-groups x 32 o-groups
    const int il = ig * 4;

    if (qmode) {
        const float* zsrc = zh + (size_t)b * CD_ * N_ + i0;
#pragma unroll
        for (int rep = 0; rep < 4; ++rep) {
            int idx = tid + rep * 256;
            int c = idx >> 3, f = idx & 7;
            *(float4*)&zt[c * 36 + f * 4] = *(const float4*)&zsrc[(size_t)c * N_ + f * 4];
        }
        __syncthreads();
        const float* wr0 = Wq + (size_t)(og * 4 + 0) * CD_;
        const float* wr1 = Wq + (size_t)(og * 4 + 1) * CD_;
        const float* wr2 = Wq + (size_t)(og * 4 + 2) * CD_;
        const float* wr3 = Wq + (size_t)(og * 4 + 3) * CD_;
        float acc[4][4];
#pragma unroll
        for (int oi = 0; oi < 4; ++oi) {
            float bb = bq[og * 4 + oi];
#pragma unroll
            for (int ri = 0; ri < 4; ++ri) acc[ri][oi] = bb;
        }
#pragma unroll 2
        for (int c4 = 0; c4 < 32; ++c4) {
            float4 w0 = *(const float4*)&wr0[c4 * 4];
            float4 w1 = *(const float4*)&wr1[c4 * 4];
            float4 w2 = *(const float4*)&wr2[c4 * 4];
            float4 w3 = *(const float4*)&wr3[c4 * 4];
            float ww[4][4] = {{w0.x,w1.x,w2.x,w3.x},{w0.y,w1.y,w2.y,w3.y},
                              {w0.z,w1.z,w2.z,w3.z},{w0.w,w1.w,w2.w,w3.w}};
#pragma unroll
            for (int cc = 0; cc < 4; ++cc) {
                float4 zr = *(float4*)&zt[(c4 * 4 + cc) * 36 + il];
                float zz[4] = {zr.x, zr.y, zr.z, zr.w};
#pragma unroll
                for (int ri = 0; ri < 4; ++ri)
#pragma unroll
                    for (int oi = 0; oi < 4; ++oi)
                        acc[ri][oi] = fmaf(zz[ri], ww[cc][oi], acc[ri][oi]);
            }
        }
#pragma unroll
        for (int ri = 0; ri < 4; ++ri) {
            unsigned w = pack4fp8(acc[ri][0] * LOG2E_, acc[ri][1] * LOG2E_,
                                  acc[ri][2] * LOG2E_, acc[ri][3] * LOG2E_);
            *(unsigned*)&qb8[((size_t)b * N_ + i0 + il + ri) * CD_ + og * 4] = w;
        }
    } else {
        const float* zsrc = zm + (size_t)b * CM_ * N_ + i0;
#pragma unroll
        for (int rep = 0; rep < 2; ++rep) {
            int idx = tid + rep * 256;
            int c = idx >> 3, f = idx & 7;
            *(float4*)&zt[c * 36 + f * 4] = *(const float4*)&zsrc[(size_t)c * N_ + f * 4];
        }
        __syncthreads();
        const float* kr0 = Wk + (size_t)(og * 4 + 0) * CM_;
        const float* kr1 = Wk + (size_t)(og * 4 + 1) * CM_;
        const float* kr2 = Wk + (size_t)(og * 4 + 2) * CM_;
        const float* kr3 = Wk + (size_t)(og * 4 + 3) * CM_;
        const float* vr0 = Wv + (size_t)(og * 4 + 0) * CM_;
        const float* vr1 = Wv + (size_t)(og * 4 + 1) * CM_;
        const float* vr2 = Wv + (size_t)(og * 4 + 2) * CM_;
        const float* vr3 = Wv + (size_t)(og * 4 + 3) * CM_;
        float ak[4][4], av[4][4];
#pragma unroll
        for (int oi = 0; oi < 4; ++oi) {
            float bk0 = bk[og * 4 + oi], bv0 = bv[og * 4 + oi];
#pragma unroll
            for (int ri = 0; ri < 4; ++ri) { ak[ri][oi] = bk0; av[ri][oi] = bv0; }
        }
#pragma unroll 2
        for (int c4 = 0; c4 < 16; ++c4) {
            float4 k0 = *(const float4*)&kr0[c4 * 4];
            float4 k1 = *(const float4*)&kr1[c4 * 4];
            float4 k2 = *(const float4*)&kr2[c4 * 4];
            float4 k3 = *(const float4*)&kr3[c4 * 4];
            float4 v0 = *(const float4*)&vr0[c4 * 4];
            float4 v1 = *(const float4*)&vr1[c4 * 4];
            float4 v2 = *(const float4*)&vr2[c4 * 4];
            float4 v3 = *(const float4*)&vr3[c4 * 4];
            float kk[4][4] = {{k0.x,k1.x,k2.x,k3.x},{k0.y,k1.y,k2.y,k3.y},
                              {k0.z,k1.z,k2.z,k3.z},{k0.w,k1.w,k2.w,k3.w}};
            float vv[4][4] = {{v0.x,v1.x,v2.x,v3.x},{v0.y,v1.y,v2.y,v3.y},
                              {v0.z,v1.z,v2.z,v3.z},{v0.w,v1.w,v2.w,v3.w}};
#pragma unroll
            for (int cc = 0; cc < 4; ++cc) {
                float4 zr = *(float4*)&zt[(c4 * 4 + cc) * 36 + il];
                float zz[4] = {zr.x, zr.y, zr.z, zr.w};
#pragma unroll
                for (int ri = 0; ri < 4; ++ri)
#pragma unroll
                    for (int oi = 0; oi < 4; ++oi) {
                        ak[ri][oi] = fmaf(zz[ri], kk[cc][oi], ak[ri][oi]);
                        av[ri][oi] = fmaf(zz[ri], vv[cc][oi], av[ri][oi]);
                    }
            }
        }
#pragma unroll
        for (int ri = 0; ri < 4; ++ri) {
            unsigned w = pack4fp8(ak[ri][0], ak[ri][1], ak[ri][2], ak[ri][3]);
            *(unsigned*)&kb8[((size_t)b * N_ + i0 + il + ri) * CD_ + og * 4] = w;
        }
        const size_t vbase = (size_t)b * CD_ * N_;
#pragma unroll
        for (int oi = 0; oi < 4; ++oi) {
            uint2 pk = make_uint2(pack2bf(av[0][oi], av[1][oi]),
                                  pack2bf(av[2][oi], av[3][oi]));
            *(uint2*)&vb[vbase + (size_t)(og * 4 + oi) * N_ + i0 + il] = pk;
        }
    }
}

// ---------------- flash: fp8 K persistent in LDS (40 KB), barrier-free j-loop ----------------
// QK via mfma_f32_32x32x16_fp8_fp8 (split acc chain); PV bf16; 3 blocks/CU.
__global__ __launch_bounds__(256, 3)
void flash8(const unsigned char* __restrict__ qb8, const unsigned char* __restrict__ kb8,
            const short* __restrict__ vb, unsigned short* __restrict__ Op,
            float* __restrict__ ml)
{
    __shared__ unsigned char Ks8[JSEG_ * 128];   // 40 KB, chunk-swizzled c' = c ^ (j&7)

    const int tid   = threadIdx.x;
    const int wave  = tid >> 6;
    const int lane  = tid & 63;
    const int m5    = lane & 31;
    const int h     = lane >> 5;

    const int bid = blockIdx.x;
    const int s   = bid % SEG_;
    const int bIt = bid / SEG_;                  // 0..99
    const int b   = bIt >= 50 ? 1 : 0;
    const int it  = bIt - b * 50;
    const int i0  = it * 128;
    const int jbase = s * JSEG_;

    const unsigned char* qbp = qb8 + (size_t)b * N_ * CD_;
    const unsigned char* kbp = kb8 + (size_t)b * N_ * CD_;
    const short* vbp = vb + (size_t)b * CD_ * N_;

    // stage K segment: 320 rows x 128 B = 2560 x 16B chunks; wave covers 80 rows
    // instr tt: rows wave*80 + tt*8 + (lane>>3); LDS dst = contiguous lane*16
#pragma unroll
    for (int tt = 0; tt < 10; ++tt) {
        int rbase = wave * 80 + tt * 8;
        const unsigned char* g = kbp + (size_t)(jbase + rbase + (lane >> 3)) * 128
                                 + (((lane & 7) ^ (lane >> 3)) << 4);
        __builtin_amdgcn_global_load_lds(
            (const __attribute__((address_space(1))) void*)g,
            (__attribute__((address_space(3))) void*)&Ks8[rbase * 128], 16, 0, 0);
    }

    // Q B-frags (fp8): lane i = m5; qf[kw] = bytes [kw*16 + 8h, +8) of row i
    const int irow = i0 + wave * 32 + m5;
    const unsigned char* qrow = qbp + (size_t)irow * CD_;
    long qf[8];
#pragma unroll
    for (int kw = 0; kw < 8; ++kw)
        qf[kw] = *(const long*)(qrow + kw * 16 + 8 * h);

    // hoisted V row pointers
    const short* vr[4];
#pragma unroll
    for (int os = 0; os < 4; ++os)
        vr[os] = vbp + (size_t)(os * 32 + m5) * N_ + 8 * h;

    f32x16 acc[4];
#pragma unroll
    for (int os = 0; os < 4; ++os)
#pragma unroll
        for (int r2 = 0; r2 < 16; ++r2) acc[os][r2] = 0.f;
    float lrun = 0.f;

    __syncthreads();   // K segment staged (only barrier before epilogue)

#pragma unroll 1
    for (int jti = 0; jti < NJT_; ++jti) {
        const int jl = jti * JT_;
        const int jt = jbase + jl;

#pragma unroll
        for (int jc = 0; jc < 2; ++jc) {
            const int jrow = jl + jc * 32 + m5;
            const unsigned char* krow = &Ks8[jrow * 128 + 8 * h];
            const int sw = (m5 & 7) << 4;
            // QK^T fp8: split accumulator chain (kw 0-3 / 4-7)
            f32x16 s0, s1;
#pragma unroll
            for (int r2 = 0; r2 < 16; ++r2) { s0[r2] = 0.f; s1[r2] = 0.f; }
#pragma unroll
            for (int kw = 0; kw < 4; ++kw) {
                long kf = *(const long*)(krow + ((kw << 4) ^ sw));
                s0 = __builtin_amdgcn_mfma_f32_32x32x16_fp8_fp8(kf, qf[kw], s0, 0, 0, 0);
            }
#pragma unroll
            for (int kw = 4; kw < 8; ++kw) {
                long kf = *(const long*)(krow + ((kw << 4) ^ sw));
                s1 = __builtin_amdgcn_mfma_f32_32x32x16_fp8_fp8(kf, qf[kw], s1, 0, 0, 0);
            }
            // P = exp2(s' - C2), pack bf16 pairs, accumulate l
            unsigned pk[8], oth[8];
#pragma unroll
            for (int p = 0; p < 8; ++p) {
                float e0 = exp2f((s0[2 * p]     + s1[2 * p])     - C2_);
                float e1 = exp2f((s0[2 * p + 1] + s1[2 * p + 1]) - C2_);
                lrun += e0 + e1;
                pk[p] = pack2bf(e0, e1);
            }
#pragma unroll
            for (int p = 0; p < 8; ++p) oth[p] = __shfl_xor((int)pk[p], 32);
            unsigned fr0[4], fr1[4];
#pragma unroll
            for (int u = 0; u < 2; ++u) {
                fr0[u]     = h ? oth[u + 2] : pk[u];
                fr0[u + 2] = h ? pk[u + 2]  : oth[u];
                fr1[u]     = h ? oth[u + 6] : pk[u + 4];
                fr1[u + 2] = h ? pk[u + 6]  : oth[u + 4];
            }
            // PV: two 16-j chunks of this jc
#pragma unroll
            for (int X = 0; X < 2; ++X) {
                union { unsigned u[4]; bf16x8 v; } pf;
#pragma unroll
                for (int u = 0; u < 4; ++u) pf.u[u] = X ? fr1[u] : fr0[u];
                const int joff = jt + jc * 32 + X * 16;
#pragma unroll
                for (int os = 0; os < 4; ++os) {
                    bf16x8 vf = *(const bf16x8*)(vr[os] + joff);
                    acc[os] = __builtin_amdgcn_mfma_f32_32x32x16_bf16(vf, pf.v, acc[os], 0, 0, 0);
                }
            }
        }
    }

    // l per row
    float lt = lrun + __shfl_xor(lrun, 32);
    if (h == 0) ml[((size_t)bIt * SEG_ + s) * 128 + wave * 32 + m5] = lt;

    __syncthreads();   // waves done reading Ks8; reuse as O transpose buffer

    // epilogue: pack O tile (128i x 128o) to bf16 in LDS (32 KB), swizzled; coalesced store
    uint2* Of2 = (uint2*)&Ks8[0];        // [i 128][uint2 32]
    const int il_ = wave * 32 + m5;
#pragma unroll
    for (int os = 0; os < 4; ++os) {
#pragma unroll
        for (int g2 = 0; g2 < 4; ++g2) {
            int q = os * 8 + 2 * g2 + h;
            int p = q ^ m5;
            Of2[il_ * 32 + p] = make_uint2(pack2bf(acc[os][4 * g2], acc[os][4 * g2 + 1]),
                                           pack2bf(acc[os][4 * g2 + 2], acc[os][4 * g2 + 3]));
        }
    }
    __syncthreads();
    uint2* opb = (uint2*)(Op + ((size_t)bIt * SEG_ + s) * (128 * CD_));
#pragma unroll
    for (int u = 0; u < 16; ++u) {
        int G = u * 256 + tid;
        int i = G >> 5;
        int q = G & 31;
        int p = q ^ (i & 31);
        opb[G] = Of2[i * 32 + p];
    }
}

// ---------------- combine SEG_ bf16 partials -> out = gamma*SumO/Suml + z_hsi ----------------
__global__ __launch_bounds__(256, 4)
void combine5(const unsigned short* __restrict__ Op, const float* __restrict__ ml,
              const float* __restrict__ z_hsi, const float* __restrict__ gamma,
              float* __restrict__ out)
{
    __shared__ float T[16 * 132];
    __shared__ float fbuf[128];
    const int tid = threadIdx.x;
    const int bIt = blockIdx.x >> 3;
    const int os  = blockIdx.x & 7;
    const int b   = bIt >= 50 ? 1 : 0;
    const int it  = bIt - b * 50;
    const int i0  = it * 128;
    const float g = gamma[0];

    if (tid < 128) {
        float den = 0.f;
#pragma unroll
        for (int s2 = 0; s2 < SEG_; ++s2)
            den += ml[((size_t)bIt * SEG_ + s2) * 128 + tid];
        fbuf[tid] = g / den;
    }
    __syncthreads();
    {
        const int i = tid >> 1, oc = tid & 1;
        const unsigned short* base = Op + (size_t)bIt * SEG_ * (128 * CD_)
                                     + (size_t)i * CD_ + os * 16 + oc * 8;
        float a[8] = {0.f, 0.f, 0.f, 0.f, 0.f, 0.f, 0.f, 0.f};
#pragma unroll
        for (int s2 = 0; s2 < SEG_; ++s2) {
            uint4 u = *(const uint4*)&base[(size_t)s2 * (128 * CD_)];
            a[0] += blo(u.x); a[1] += bhi(u.x);
            a[2] += blo(u.y); a[3] += bhi(u.y);
            a[4] += blo(u.z); a[5] += bhi(u.z);
            a[6] += blo(u.w); a[7] += bhi(u.w);
        }
        const float f = fbuf[i];
#pragma unroll
        for (int o = 0; o < 8; ++o) T[(oc * 8 + o) * 132 + i] = a[o] * f;
    }
    __syncthreads();
    {
        const int ol = tid >> 4;
        const int ic = (tid & 15) * 8;
        const int o  = os * 16 + ol;
        const size_t gbase = ((size_t)b * CD_ + o) * N_ + i0 + ic;
        float4 t0 = *(float4*)&T[ol * 132 + ic];
        float4 t1 = *(float4*)&T[ol * 132 + ic + 4];
        float4 z0 = *(const float4*)&z_hsi[gbase];
        float4 z1 = *(const float4*)&z_hsi[gbase + 4];
        *(float4*)&out[gbase]     = make_float4(t0.x + z0.x, t0.y + z0.y, t0.z + z0.z, t0.w + z0.w);
        *(float4*)&out[gbase + 4] = make_float4(t1.x + z1.x, t1.y + z1.y, t1.z + z1.z, t1.w + z1.w);
    }
}

extern "C" void kernel_launch(void* const* d_in, const int* in_sizes, int n_in,
                              void* d_out, int out_size, void* d_ws, size_t ws_size,
                              hipStream_t stream) {
    const float* z_hsi = (const float*)d_in[0];
    const float* z_msi = (const float*)d_in[1];
    const float* Wq    = (const float*)d_in[2];
    const float* bq    = (const float*)d_in[3];
    const float* Wk    = (const float*)d_in[4];
    const float* bk    = (const float*)d_in[5];
    const float* Wv    = (const float*)d_in[6];
    const float* bv    = (const float*)d_in[7];
    const float* gamma = (const float*)d_in[8];
    float* out = (float*)d_out;

    const size_t nrow = (size_t)B_ * N_ * CD_;             // 1,638,400
    unsigned char* qb8 = (unsigned char*)d_ws;             // 1.64 MB fp8
    unsigned char* kb8 = qb8 + nrow;                       // 1.64 MB fp8
    short* vb = (short*)(kb8 + nrow);                      // 3.28 MB bf16
    unsigned short* Op = (unsigned short*)(vb + nrow);     // 100*20*128*128 bf16 = 65.5 MB
    float* ml = (float*)(Op + (size_t)NBIT_ * SEG_ * 128 * CD_);

    proj4<<<dim3(800), dim3(256), 0, stream>>>(z_hsi, z_msi, Wq, bq, Wk, bk, Wv, bv,
                                               qb8, kb8, vb);
    flash8<<<dim3(NBIT_ * SEG_), dim3(256), 0, stream>>>(qb8, kb8, vb, Op, ml);
    combine5<<<dim3(800), dim3(256), 0, stream>>>(Op, ml, z_hsi, gamma, out);
}

// Round 8
// 227.167 us; speedup vs baseline: 1.0164x; 1.0164x over previous
//
#include <hip/hip_runtime.h>
#include <hip/hip_bf16.h>

#define B_    2
#define N_    6400
#define CD_   128
#define CM_   64
#define SEG_  20
#define JSEG_ (N_ / SEG_)    // 320
#define JT_   64
#define NJT_  (JSEG_ / JT_)  // 5
#define NBIT_ 100            // i-tiles of 128 total (2 b x 50)
#define LOG2E_ 1.44269504f
#define C2_    36.0673757f   // 25 * log2(e)

typedef __attribute__((ext_vector_type(8)))  short bf16x8;
typedef __attribute__((ext_vector_type(16))) float f32x16;

static __device__ __forceinline__ unsigned pack2bf(float a, float b) {
    union { float f; unsigned u; } x, y; x.f = a; y.f = b;
    return __builtin_amdgcn_perm(y.u + 0x8000u, x.u + 0x8000u, 0x07060302u);
}
// gfx950 packed f32->bf16 convert (RNE), 1 instruction
static __device__ __forceinline__ unsigned packbf16(float a, float b) {
    unsigned r;
    asm("v_cvt_pk_bf16_f32 %0, %1, %2" : "=v"(r) : "v"(a), "v"(b));
    return r;
}
static __device__ __forceinline__ float blo(unsigned u) {
    union { unsigned u; float f; } c; c.u = u << 16; return c.f;
}
static __device__ __forceinline__ float bhi(unsigned u) {
    union { unsigned u; float f; } c; c.u = u & 0xffff0000u; return c.f;
}
// pack 4 floats -> 4 fp8 e4m3 bytes
static __device__ __forceinline__ unsigned pack4fp8(float a, float b, float c, float d) {
    int w = __builtin_amdgcn_cvt_pk_fp8_f32(a, b, 0, false);
    w = __builtin_amdgcn_cvt_pk_fp8_f32(c, d, w, true);
    return (unsigned)w;
}

// ---------------- fused projections ----------------
// blocks [0,400): q (fp8, pre-scaled by log2e) from z_hsi; [400,800): k (fp8), v (bf16)
__global__ __launch_bounds__(256, 4)
void proj4(const float* __restrict__ zh, const float* __restrict__ zm,
           const float* __restrict__ Wq, const float* __restrict__ bq,
           const float* __restrict__ Wk, const float* __restrict__ bk,
           const float* __restrict__ Wv, const float* __restrict__ bv,
           unsigned char* __restrict__ qb8, unsigned char* __restrict__ kb8,
           short* __restrict__ vb)
{
    __shared__ float zt[128 * 36];   // [c][i 32], stride 36
    const int tid = threadIdx.x;
    int bid = blockIdx.x;
    const int qmode = bid < 400;
    if (!qmode) bid -= 400;
    const int b  = bid / 200;
    const int r  = bid % 200;
    const int i0 = r * 32;
    const int ig = tid & 7, og = tid >> 3;       // 8 i-groups x 32 o-groups
    const int il = ig * 4;

    if (qmode) {
        const float* zsrc = zh + (size_t)b * CD_ * N_ + i0;
#pragma unroll
        for (int rep = 0; rep < 4; ++rep) {
            int idx = tid + rep * 256;
            int c = idx >> 3, f = idx & 7;
            *(float4*)&zt[c * 36 + f * 4] = *(const float4*)&zsrc[(size_t)c * N_ + f * 4];
        }
        __syncthreads();
        const float* wr0 = Wq + (size_t)(og * 4 + 0) * CD_;
        const float* wr1 = Wq + (size_t)(og * 4 + 1) * CD_;
        const float* wr2 = Wq + (size_t)(og * 4 + 2) * CD_;
        const float* wr3 = Wq + (size_t)(og * 4 + 3) * CD_;
        float acc[4][4];
#pragma unroll
        for (int oi = 0; oi < 4; ++oi) {
            float bb = bq[og * 4 + oi];
#pragma unroll
            for (int ri = 0; ri < 4; ++ri) acc[ri][oi] = bb;
        }
#pragma unroll 2
        for (int c4 = 0; c4 < 32; ++c4) {
            float4 w0 = *(const float4*)&wr0[c4 * 4];
            float4 w1 = *(const float4*)&wr1[c4 * 4];
            float4 w2 = *(const float4*)&wr2[c4 * 4];
            float4 w3 = *(const float4*)&wr3[c4 * 4];
            float ww[4][4] = {{w0.x,w1.x,w2.x,w3.x},{w0.y,w1.y,w2.y,w3.y},
                              {w0.z,w1.z,w2.z,w3.z},{w0.w,w1.w,w2.w,w3.w}};
#pragma unroll
            for (int cc = 0; cc < 4; ++cc) {
                float4 zr = *(float4*)&zt[(c4 * 4 + cc) * 36 + il];
                float zz[4] = {zr.x, zr.y, zr.z, zr.w};
#pragma unroll
                for (int ri = 0; ri < 4; ++ri)
#pragma unroll
                    for (int oi = 0; oi < 4; ++oi)
                        acc[ri][oi] = fmaf(zz[ri], ww[cc][oi], acc[ri][oi]);
            }
        }
#pragma unroll
        for (int ri = 0; ri < 4; ++ri) {
            unsigned w = pack4fp8(acc[ri][0] * LOG2E_, acc[ri][1] * LOG2E_,
                                  acc[ri][2] * LOG2E_, acc[ri][3] * LOG2E_);
            *(unsigned*)&qb8[((size_t)b * N_ + i0 + il + ri) * CD_ + og * 4] = w;
        }
    } else {
        const float* zsrc = zm + (size_t)b * CM_ * N_ + i0;
#pragma unroll
        for (int rep = 0; rep < 2; ++rep) {
            int idx = tid + rep * 256;
            int c = idx >> 3, f = idx & 7;
            *(float4*)&zt[c * 36 + f * 4] = *(const float4*)&zsrc[(size_t)c * N_ + f * 4];
        }
        __syncthreads();
        const float* kr0 = Wk + (size_t)(og * 4 + 0) * CM_;
        const float* kr1 = Wk + (size_t)(og * 4 + 1) * CM_;
        const float* kr2 = Wk + (size_t)(og * 4 + 2) * CM_;
        const float* kr3 = Wk + (size_t)(og * 4 + 3) * CM_;
        const float* vr0 = Wv + (size_t)(og * 4 + 0) * CM_;
        const float* vr1 = Wv + (size_t)(og * 4 + 1) * CM_;
        const float* vr2 = Wv + (size_t)(og * 4 + 2) * CM_;
        const float* vr3 = Wv + (size_t)(og * 4 + 3) * CM_;
        float ak[4][4], av[4][4];
#pragma unroll
        for (int oi = 0; oi < 4; ++oi) {
            float bk0 = bk[og * 4 + oi], bv0 = bv[og * 4 + oi];
#pragma unroll
            for (int ri = 0; ri < 4; ++ri) { ak[ri][oi] = bk0; av[ri][oi] = bv0; }
        }
#pragma unroll 2
        for (int c4 = 0; c4 < 16; ++c4) {
            float4 k0 = *(const float4*)&kr0[c4 * 4];
            float4 k1 = *(const float4*)&kr1[c4 * 4];
            float4 k2 = *(const float4*)&kr2[c4 * 4];
            float4 k3 = *(const float4*)&kr3[c4 * 4];
            float4 v0 = *(const float4*)&vr0[c4 * 4];
            float4 v1 = *(const float4*)&vr1[c4 * 4];
            float4 v2 = *(const float4*)&vr2[c4 * 4];
            float4 v3 = *(const float4*)&vr3[c4 * 4];
            float kk[4][4] = {{k0.x,k1.x,k2.x,k3.x},{k0.y,k1.y,k2.y,k3.y},
                              {k0.z,k1.z,k2.z,k3.z},{k0.w,k1.w,k2.w,k3.w}};
            float vv[4][4] = {{v0.x,v1.x,v2.x,v3.x},{v0.y,v1.y,v2.y,v3.y},
                              {v0.z,v1.z,v2.z,v3.z},{v0.w,v1.w,v2.w,v3.w}};
#pragma unroll
            for (int cc = 0; cc < 4; ++cc) {
                float4 zr = *(float4*)&zt[(c4 * 4 + cc) * 36 + il];
                float zz[4] = {zr.x, zr.y, zr.z, zr.w};
#pragma unroll
                for (int ri = 0; ri < 4; ++ri)
#pragma unroll
                    for (int oi = 0; oi < 4; ++oi) {
                        ak[ri][oi] = fmaf(zz[ri], kk[cc][oi], ak[ri][oi]);
                        av[ri][oi] = fmaf(zz[ri], vv[cc][oi], av[ri][oi]);
                    }
            }
        }
#pragma unroll
        for (int ri = 0; ri < 4; ++ri) {
            unsigned w = pack4fp8(ak[ri][0], ak[ri][1], ak[ri][2], ak[ri][3]);
            *(unsigned*)&kb8[((size_t)b * N_ + i0 + il + ri) * CD_ + og * 4] = w;
        }
        const size_t vbase = (size_t)b * CD_ * N_;
#pragma unroll
        for (int oi = 0; oi < 4; ++oi) {
            uint2 pk = make_uint2(pack2bf(av[0][oi], av[1][oi]),
                                  pack2bf(av[2][oi], av[3][oi]));
            *(uint2*)&vb[vbase + (size_t)(og * 4 + oi) * N_ + i0 + il] = pk;
        }
    }
}

// ---------------- flash: fp8 K persistent in LDS (40 KB), barrier-free j-loop ----------------
// V loads issued EARLY (X0 before QK chain, X1 before exp) so L2 latency is hidden.
__global__ __launch_bounds__(256, 3)
void flash9(const unsigned char* __restrict__ qb8, const unsigned char* __restrict__ kb8,
            const short* __restrict__ vb, unsigned short* __restrict__ Op,
            float* __restrict__ ml)
{
    __shared__ unsigned char Ks8[JSEG_ * 128];   // 40 KB, chunk-swizzled c' = c ^ (j&7)

    const int tid   = threadIdx.x;
    const int wave  = tid >> 6;
    const int lane  = tid & 63;
    const int m5    = lane & 31;
    const int h     = lane >> 5;

    const int bid = blockIdx.x;
    const int s   = bid % SEG_;
    const int bIt = bid / SEG_;                  // 0..99
    const int b   = bIt >= 50 ? 1 : 0;
    const int it  = bIt - b * 50;
    const int i0  = it * 128;
    const int jbase = s * JSEG_;

    const unsigned char* qbp = qb8 + (size_t)b * N_ * CD_;
    const unsigned char* kbp = kb8 + (size_t)b * N_ * CD_;
    const short* vbp = vb + (size_t)b * CD_ * N_;

    // stage K segment: 320 rows x 128 B; wave covers 80 rows
#pragma unroll
    for (int tt = 0; tt < 10; ++tt) {
        int rbase = wave * 80 + tt * 8;
        const unsigned char* g = kbp + (size_t)(jbase + rbase + (lane >> 3)) * 128
                                 + (((lane & 7) ^ (lane >> 3)) << 4);
        __builtin_amdgcn_global_load_lds(
            (const __attribute__((address_space(1))) void*)g,
            (__attribute__((address_space(3))) void*)&Ks8[rbase * 128], 16, 0, 0);
    }

    // Q B-frags (fp8): lane i = m5
    const int irow = i0 + wave * 32 + m5;
    const unsigned char* qrow = qbp + (size_t)irow * CD_;
    long qf[8];
#pragma unroll
    for (int kw = 0; kw < 8; ++kw)
        qf[kw] = *(const long*)(qrow + kw * 16 + 8 * h);

    // hoisted V row pointers
    const short* vr[4];
#pragma unroll
    for (int os = 0; os < 4; ++os)
        vr[os] = vbp + (size_t)(os * 32 + m5) * N_ + 8 * h;

    f32x16 acc[4];
#pragma unroll
    for (int os = 0; os < 4; ++os)
#pragma unroll
        for (int r2 = 0; r2 < 16; ++r2) acc[os][r2] = 0.f;
    float lrun = 0.f;

    __syncthreads();   // K segment staged (only barrier before epilogue)

#pragma unroll 1
    for (int jti = 0; jti < NJT_; ++jti) {
        const int jl = jti * JT_;
        const int jt = jbase + jl;

#pragma unroll
        for (int jc = 0; jc < 2; ++jc) {
            const int jrow = jl + jc * 32 + m5;
            const unsigned char* krow = &Ks8[jrow * 128 + 8 * h];
            const int sw = (m5 & 7) << 4;
            const int joff = jt + jc * 32;

            // EARLY V issue, group X0 (covered by QK chain + exp)
            bf16x8 vf0[4];
#pragma unroll
            for (int os = 0; os < 4; ++os)
                vf0[os] = *(const bf16x8*)(vr[os] + joff);

            // QK^T fp8: split accumulator chain (kw 0-3 / 4-7)
            f32x16 s0, s1;
#pragma unroll
            for (int r2 = 0; r2 < 16; ++r2) { s0[r2] = 0.f; s1[r2] = 0.f; }
#pragma unroll
            for (int kw = 0; kw < 4; ++kw) {
                long kf = *(const long*)(krow + ((kw << 4) ^ sw));
                s0 = __builtin_amdgcn_mfma_f32_32x32x16_fp8_fp8(kf, qf[kw], s0, 0, 0, 0);
            }
#pragma unroll
            for (int kw = 4; kw < 8; ++kw) {
                long kf = *(const long*)(krow + ((kw << 4) ^ sw));
                s1 = __builtin_amdgcn_mfma_f32_32x32x16_fp8_fp8(kf, qf[kw], s1, 0, 0, 0);
            }
            // fold s1 into s0 (frees s1 before X1 loads)
#pragma unroll
            for (int r2 = 0; r2 < 16; ++r2) s0[r2] += s1[r2];

            // EARLY V issue, group X1 (covered by exp/pack/shfl)
            bf16x8 vf1[4];
#pragma unroll
            for (int os = 0; os < 4; ++os)
                vf1[os] = *(const bf16x8*)(vr[os] + joff + 16);

            // P = exp2(s - C2), pack bf16 pairs, accumulate l
            unsigned pk[8], oth[8];
#pragma unroll
            for (int p = 0; p < 8; ++p) {
                float e0 = exp2f(s0[2 * p]     - C2_);
                float e1 = exp2f(s0[2 * p + 1] - C2_);
                lrun += e0 + e1;
                pk[p] = packbf16(e0, e1);
            }
#pragma unroll
            for (int p = 0; p < 8; ++p) oth[p] = __shfl_xor((int)pk[p], 32);
            unsigned fr0[4], fr1[4];
#pragma unroll
            for (int u = 0; u < 2; ++u) {
                fr0[u]     = h ? oth[u + 2] : pk[u];
                fr0[u + 2] = h ? pk[u + 2]  : oth[u];
                fr1[u]     = h ? oth[u + 6] : pk[u + 4];
                fr1[u + 2] = h ? pk[u + 6]  : oth[u + 4];
            }
            // PV: two 16-j chunks of this jc
            {
                union { unsigned u[4]; bf16x8 v; } pf;
#pragma unroll
                for (int u = 0; u < 4; ++u) pf.u[u] = fr0[u];
#pragma unroll
                for (int os = 0; os < 4; ++os)
                    acc[os] = __builtin_amdgcn_mfma_f32_32x32x16_bf16(vf0[os], pf.v, acc[os], 0, 0, 0);
            }
            {
                union { unsigned u[4]; bf16x8 v; } pf;
#pragma unroll
                for (int u = 0; u < 4; ++u) pf.u[u] = fr1[u];
#pragma unroll
                for (int os = 0; os < 4; ++os)
                    acc[os] = __builtin_amdgcn_mfma_f32_32x32x16_bf16(vf1[os], pf.v, acc[os], 0, 0, 0);
            }
        }
    }

    // l per row
    float lt = lrun + __shfl_xor(lrun, 32);
    if (h == 0) ml[((size_t)bIt * SEG_ + s) * 128 + wave * 32 + m5] = lt;

    __syncthreads();   // waves done reading Ks8; reuse as O transpose buffer

    // epilogue: pack O tile (128i x 128o) to bf16 in LDS (32 KB), swizzled; coalesced store
    uint2* Of2 = (uint2*)&Ks8[0];        // [i 128][uint2 32]
    const int il_ = wave * 32 + m5;
#pragma unroll
    for (int os = 0; os < 4; ++os) {
#pragma unroll
        for (int g2 = 0; g2 < 4; ++g2) {
            int q = os * 8 + 2 * g2 + h;
            int p = q ^ m5;
            Of2[il_ * 32 + p] = make_uint2(packbf16(acc[os][4 * g2], acc[os][4 * g2 + 1]),
                                           packbf16(acc[os][4 * g2 + 2], acc[os][4 * g2 + 3]));
        }
    }
    __syncthreads();
    uint2* opb = (uint2*)(Op + ((size_t)bIt * SEG_ + s) * (128 * CD_));
#pragma unroll
    for (int u = 0; u < 16; ++u) {
        int G = u * 256 + tid;
        int i = G >> 5;
        int q = G & 31;
        int p = q ^ (i & 31);
        opb[G] = Of2[i * 32 + p];
    }
}

// ---------------- combine SEG_ bf16 partials -> out = gamma*SumO/Suml + z_hsi ----------------
__global__ __launch_bounds__(256, 4)
void combine5(const unsigned short* __restrict__ Op, const float* __restrict__ ml,
              const float* __restrict__ z_hsi, const float* __restrict__ gamma,
              float* __restrict__ out)
{
    __shared__ float T[16 * 132];
    __shared__ float fbuf[128];
    const int tid = threadIdx.x;
    const int bIt = blockIdx.x >> 3;
    const int os  = blockIdx.x & 7;
    const int b   = bIt >= 50 ? 1 : 0;
    const int it  = bIt - b * 50;
    const int i0  = it * 128;
    const float g = gamma[0];

    if (tid < 128) {
        float den = 0.f;
#pragma unroll
        for (int s2 = 0; s2 < SEG_; ++s2)
            den += ml[((size_t)bIt * SEG_ + s2) * 128 + tid];
        fbuf[tid] = g / den;
    }
    __syncthreads();
    {
        const int i = tid >> 1, oc = tid & 1;
        const unsigned short* base = Op + (size_t)bIt * SEG_ * (128 * CD_)
                                     + (size_t)i * CD_ + os * 16 + oc * 8;
        float a[8] = {0.f, 0.f, 0.f, 0.f, 0.f, 0.f, 0.f, 0.f};
#pragma unroll
        for (int s2 = 0; s2 < SEG_; ++s2) {
            uint4 u = *(const uint4*)&base[(size_t)s2 * (128 * CD_)];
            a[0] += blo(u.x); a[1] += bhi(u.x);
            a[2] += blo(u.y); a[3] += bhi(u.y);
            a[4] += blo(u.z); a[5] += bhi(u.z);
            a[6] += blo(u.w); a[7] += bhi(u.w);
        }
        const float f = fbuf[i];
#pragma unroll
        for (int o = 0; o < 8; ++o) T[(oc * 8 + o) * 132 + i] = a[o] * f;
    }
    __syncthreads();
    {
        const int ol = tid >> 4;
        const int ic = (tid & 15) * 8;
        const int o  = os * 16 + ol;
        const size_t gbase = ((size_t)b * CD_ + o) * N_ + i0 + ic;
        float4 t0 = *(float4*)&T[ol * 132 + ic];
        float4 t1 = *(float4*)&T[ol * 132 + ic + 4];
        float4 z0 = *(const float4*)&z_hsi[gbase];
        float4 z1 = *(const float4*)&z_hsi[gbase + 4];
        *(float4*)&out[gbase]     = make_float4(t0.x + z0.x, t0.y + z0.y, t0.z + z0.z, t0.w + z0.w);
        *(float4*)&out[gbase + 4] = make_float4(t1.x + z1.x, t1.y + z1.y, t1.z + z1.z, t1.w + z1.w);
    }
}

extern "C" void kernel_launch(void* const* d_in, const int* in_sizes, int n_in,
                              void* d_out, int out_size, void* d_ws, size_t ws_size,
                              hipStream_t stream) {
    const float* z_hsi = (const float*)d_in[0];
    const float* z_msi = (const float*)d_in[1];
    const float* Wq    = (const float*)d_in[2];
    const float* bq    = (const float*)d_in[3];
    const float* Wk    = (const float*)d_in[4];
    const float* bk    = (const float*)d_in[5];
    const float* Wv    = (const float*)d_in[6];
    const float* bv    = (const float*)d_in[7];
    const float* gamma = (const float*)d_in[8];
    float* out = (float*)d_out;

    const size_t nrow = (size_t)B_ * N_ * CD_;             // 1,638,400
    unsigned char* qb8 = (unsigned char*)d_ws;             // 1.64 MB fp8
    unsigned char* kb8 = qb8 + nrow;                       // 1.64 MB fp8
    short* vb = (short*)(kb8 + nrow);                      // 3.28 MB bf16
    unsigned short* Op = (unsigned short*)(vb + nrow);     // 65.5 MB bf16 partials
    float* ml = (float*)(Op + (size_t)NBIT_ * SEG_ * 128 * CD_);

    proj4<<<dim3(800), dim3(256), 0, stream>>>(z_hsi, z_msi, Wq, bq, Wk, bk, Wv, bv,
                                               qb8, kb8, vb);
    flash9<<<dim3(NBIT_ * SEG_), dim3(256), 0, stream>>>(qb8, kb8, vb, Op, ml);
    combine5<<<dim3(800), dim3(256), 0, stream>>>(Op, ml, z_hsi, gamma, out);
}